// Round 4
// baseline (321.241 us; speedup 1.0000x reference)
//
#include <hip/hip_runtime.h>
#include <hip/hip_bf16.h>

// PAM module: B=4, N=4096 (64x64), C=64.
// out[b,n,c] = gamma * sum_m softmax_row(q@k^T)[m,n] * v[m,c] + x[b,n,c]
//
// bf16 MFMA; energy recomputed. log2e folded into Wq/bq; softmax normalizer
// folded into MFMA C-init (lr = -log2(rowsum)). PV uses K=16 MFMA so the
// P fragment is built IN REGISTERS from the QK output.
// k2/k3 are BARRIER-FREE + LDS-FREE: all streamed fragments are lane-indexed
// only (wave-uniform across wid), so L1 serves the 4x duplication and waves
// slip independently (no convoying).
//  k0z: W -> W^T bf16 (Wq scaled by log2e), zero s-buffer
//  k1 : per-projection blocks (grid 768): q,k row-major bf16; v^T [c][n] bf16
//  k2 : partial rowsums s[m] += sum_n exp2(e') (n-split 8, atomic)
//  r2 : lr = -log2(s) ; out <- x
//  k3 : out += gamma * exp2(e'+lr) @ v (m-split 8, atomic, reg-P)

typedef __attribute__((ext_vector_type(8))) short short8;
typedef __attribute__((ext_vector_type(4))) short short4b;
typedef __attribute__((ext_vector_type(4))) float f32x4;
typedef __attribute__((ext_vector_type(4))) unsigned int u32x4;
typedef __attribute__((ext_vector_type(2))) unsigned int u32x2;

#define DEV static __device__ __forceinline__
#define LOG2E 1.4426950408889634f

DEV unsigned short f2bf(float f) {
    __hip_bfloat16 h = __float2bfloat16(f);
    return __builtin_bit_cast(unsigned short, h);
}
DEV unsigned int pack2(float lo, float hi) {
    return (unsigned int)f2bf(lo) | ((unsigned int)f2bf(hi) << 16);
}
DEV unsigned int pack2t(float lo, float hi) {   // truncation-pack (P>=0, no NaN)
    unsigned int ul = __builtin_bit_cast(unsigned int, lo);
    unsigned int uh = __builtin_bit_cast(unsigned int, hi);
    return (uh & 0xffff0000u) | (ul >> 16);
}
DEV f32x4 MFMA32(short8 a, short8 b, f32x4 c) {
    return __builtin_amdgcn_mfma_f32_16x16x32_bf16(a, b, c, 0, 0, 0);
}
DEV f32x4 MFMA16(short4b a, short4b b, f32x4 c) {
#if __has_builtin(__builtin_amdgcn_mfma_f32_16x16x16_bf16)
    return __builtin_amdgcn_mfma_f32_16x16x16_bf16(a, b, c, 0, 0, 0);
#elif __has_builtin(__builtin_amdgcn_mfma_f32_16x16x16bf16_1k)
    return __builtin_amdgcn_mfma_f32_16x16x16bf16_1k(a, b, c, 0, 0, 0);
#else
    f32x4 d = c;
    asm volatile("v_mfma_f32_16x16x16_bf16 %0, %1, %2, %0" : "+v"(d) : "v"(a), "v"(b));
    return d;
#endif
}
DEV float EXP2(float x) {
#if __has_builtin(__builtin_amdgcn_exp2f)
    return __builtin_amdgcn_exp2f(x);
#else
    return exp2f(x);
#endif
}

// ws layout (bytes)
#define OFF_Q    0u          // [16384][64] bf16 = 2 MB  (q' = log2e * (xWq+bq))
#define OFF_K    2097152u    // [16384][64] bf16 = 2 MB
#define OFF_VT   4194304u    // [4][64][4096] bf16 = 2 MB
#define OFF_WT   6291456u    // [3][64][64] bf16 = 24 KB
#define OFF_S    6316032u    // [16384] f32 = 64 KB (row sums, atomic)
#define OFF_LR   6381568u    // [16384] f32 = 64 KB (lr = -log2 s)

// ---------------- k0z: weight transpose (+log2e on Wq) + zero s ----------------
__global__ __launch_bounds__(256) void k0z(const float* __restrict__ Wq,
                                           const float* __restrict__ Wk,
                                           const float* __restrict__ Wv,
                                           unsigned short* __restrict__ wt,
                                           float* __restrict__ sbuf) {
    int e = blockIdx.x * 256 + threadIdx.x;   // grid 64 -> [0,16384)
    sbuf[e] = 0.0f;
    if (e < 3 * 4096) {
        int w3 = e >> 12, rem = e & 4095, f = rem >> 6, c = rem & 63;
        const float* W = (w3 == 0) ? Wq : (w3 == 1) ? Wk : Wv;
        float s = (w3 == 0) ? LOG2E : 1.0f;
        wt[e] = f2bf(W[c * 64 + f] * s);   // wt[w3][f][c] = W[c][f] * s
    }
}

// ---------------- k1: projections, one projection per block (grid 768) ----------------
__global__ __launch_bounds__(256) void k1_proj(const float* __restrict__ x,
                                               const unsigned short* __restrict__ wt,
                                               const float* __restrict__ bq,
                                               const float* __restrict__ bk,
                                               const float* __restrict__ bv,
                                               unsigned short* __restrict__ qg,
                                               unsigned short* __restrict__ kg,
                                               unsigned short* __restrict__ vtg) {
    __shared__ __align__(16) char XT[8192];
    __shared__ __align__(16) char WT1[8192];
    __shared__ __align__(16) char VTILE[9216];
    int t = threadIdx.x, blk = blockIdx.x;
    int w3 = blk >> 8, rb = blk & 255;

    {   // stage x tile (fp32 -> bf16, swizzled)
        int m = t >> 2, q4 = t & 3;
        const f32x4* xs = (const f32x4*)(x + (size_t)(rb * 64 + m) * 64 + q4 * 16);
        f32x4 fa = xs[0], f2 = xs[1], fc = xs[2], fd = xs[3];
        u32x4 u0 = { pack2(fa[0],fa[1]), pack2(fa[2],fa[3]), pack2(f2[0],f2[1]), pack2(f2[2],f2[3]) };
        u32x4 u1 = { pack2(fc[0],fc[1]), pack2(fc[2],fc[3]), pack2(fd[0],fd[1]), pack2(fd[2],fd[3]) };
        int sw = (m & 7) << 4;
        *(u32x4*)(XT + m * 128 + ((q4 * 32) ^ sw)) = u0;
        *(u32x4*)(XT + m * 128 + ((q4 * 32 + 16) ^ sw)) = u1;
    }
    {   // stage this block's W^T
        int f = t >> 2, q4 = t & 3;
        const u32x4* s = (const u32x4*)(wt + w3 * 4096 + f * 64 + q4 * 16);
        u32x4 u0 = s[0], u1 = s[1];
        int sw = (f & 7) << 4;
        *(u32x4*)(WT1 + f * 128 + ((q4 * 32) ^ sw)) = u0;
        *(u32x4*)(WT1 + f * 128 + ((q4 * 32 + 16) ^ sw)) = u1;
    }
    __syncthreads();

    int lane = t & 63, wid = t >> 6, g = lane >> 4, ln = lane & 15;
    int arow = wid * 16 + ln;
    short8 a0 = *(const short8*)(XT + arow * 128 + ((16 * g) ^ ((arow & 7) << 4)));
    short8 a1 = *(const short8*)(XT + arow * 128 + ((64 + 16 * g) ^ ((arow & 7) << 4)));
    const float* bias = (w3 == 0) ? bq : (w3 == 1) ? bk : bv;
    float bscale = (w3 == 0) ? LOG2E : 1.0f;

    #pragma unroll
    for (int fb = 0; fb < 4; ++fb) {
        int frow = fb * 16 + ln;
        short8 b0 = *(const short8*)(WT1 + frow * 128 + ((16 * g) ^ ((frow & 7) << 4)));
        short8 b1 = *(const short8*)(WT1 + frow * 128 + ((64 + 16 * g) ^ ((frow & 7) << 4)));
        f32x4 acc = {0.f, 0.f, 0.f, 0.f};
        acc = MFMA32(a0, b0, acc);
        acc = MFMA32(a1, b1, acc);
        float bval = bias[frow] * bscale;
        if (w3 < 2) {
            unsigned short* dst = (w3 == 0) ? qg : kg;
            int gr = rb * 64 + wid * 16 + 4 * g;
            #pragma unroll
            for (int r = 0; r < 4; ++r)
                dst[(size_t)(gr + r) * 64 + frow] = f2bf(acc[r] + bval);
        } else {
            unsigned short* vt = (unsigned short*)VTILE;
            int mloc = wid * 16 + 4 * g;
            #pragma unroll
            for (int r = 0; r < 4; ++r)
                vt[frow * 72 + mloc + r] = f2bf(acc[r] + bval);
        }
    }
    if (w3 == 2) {   // block-uniform branch
        __syncthreads();
        int f = t >> 2, mq = t & 3;
        u32x4 u0 = *(const u32x4*)(VTILE + f * 144 + mq * 32);
        u32x4 u1 = *(const u32x4*)(VTILE + f * 144 + mq * 32 + 16);
        int b = rb >> 6, n0 = (rb & 63) * 64;
        unsigned short* dst = vtg + (size_t)b * 262144 + f * 4096 + n0 + mq * 16;
        *(u32x4*)(dst) = u0;
        *(u32x4*)(dst + 8) = u1;
    }
}

// ---------------- k2: partial row sums (n-split 8, NO LDS, NO BARRIERS) ----------------
// grid 2048: blk = b*512 + ns*64 + mb. Wave owns 16 m rows (q frags pinned),
// streams 32 chunks of 16 n as k B-frags straight from global (L1-shared across waves).
__global__ __launch_bounds__(256, 8) void k2_rowsum(const unsigned short* __restrict__ qg,
                                                    const unsigned short* __restrict__ kg,
                                                    float* __restrict__ sbuf) {
    int t = threadIdx.x, blk = blockIdx.x;
    int b = blk >> 9, ns = (blk >> 6) & 7, mb = blk & 63;
    int m0 = mb * 64, nbase = ns * 512;
    int lane = t & 63, wid = t >> 6, g = lane >> 4, ln = lane & 15;

    const unsigned short* qr = qg + (size_t)(b * 4096 + m0 + wid * 16 + ln) * 64;
    short8 a0 = *(const short8*)(qr + 8 * g);        // q[m=wid*16+ln][c 8g..8g+7]
    short8 a1 = *(const short8*)(qr + 32 + 8 * g);   // c 32+8g..

    const unsigned short* kbase = kg + (size_t)(b * 4096 + nbase + ln) * 64 + 8 * g;
    short8 kb0 = *(const short8*)(kbase);
    short8 kb1 = *(const short8*)(kbase + 32);

    float acc0 = 0.f, acc1 = 0.f, acc2 = 0.f, acc3 = 0.f;
    for (int s = 0; s < 32; ++s) {
        short8 nb0, nb1;
        if (s < 31) {   // register prefetch of next 16-n chunk
            const unsigned short* kp = kbase + (size_t)(s + 1) * 16 * 64;
            nb0 = *(const short8*)(kp);
            nb1 = *(const short8*)(kp + 32);
        }
        f32x4 z = {0.f, 0.f, 0.f, 0.f};
        f32x4 e = MFMA32(a1, kb1, MFMA32(a0, kb0, z));
        acc0 += EXP2(e[0]); acc1 += EXP2(e[1]);
        acc2 += EXP2(e[2]); acc3 += EXP2(e[3]);
        kb0 = nb0; kb1 = nb1;
    }
    #pragma unroll
    for (int msk = 1; msk < 16; msk <<= 1) {
        acc0 += __shfl_xor(acc0, msk);
        acc1 += __shfl_xor(acc1, msk);
        acc2 += __shfl_xor(acc2, msk);
        acc3 += __shfl_xor(acc3, msk);
    }
    if (ln == 0) {
        float* base = sbuf + b * 4096 + m0 + wid * 16 + 4 * g;
        unsafeAtomicAdd(base + 0, acc0);
        unsafeAtomicAdd(base + 1, acc1);
        unsafeAtomicAdd(base + 2, acc2);
        unsafeAtomicAdd(base + 3, acc3);
    }
}

// ---------------- r2: lr = -log2(s) ; out <- x ----------------
__global__ __launch_bounds__(256) void r2_init(const float* __restrict__ sbuf,
                                               float* __restrict__ lrbuf,
                                               const float* __restrict__ x,
                                               float* __restrict__ outp) {
    int tid = blockIdx.x * 256 + threadIdx.x;   // grid 1024
    if (tid < 16384) lrbuf[tid] = -__log2f(sbuf[tid]);
    f32x4 v = *(const f32x4*)(x + 4 * (size_t)tid);
    *(f32x4*)(outp + 4 * (size_t)tid) = v;
}

// ---------------- k3: out += gamma * exp2(e'+lr) @ v  (m-split 8, NO LDS/BARRIERS) ----------------
// grid 2048: blk = b*512 + ms*64 + nb. Wave owns 16 n (k frags pinned),
// streams 32 chunks of 16 m: q A-frags + vT B-frags + lr straight from global.
__global__ __launch_bounds__(256, 6) void k3_out(const unsigned short* __restrict__ qg,
                                                 const unsigned short* __restrict__ kg,
                                                 const unsigned short* __restrict__ vtg,
                                                 const float* __restrict__ lrbuf,
                                                 const float* __restrict__ gamma,
                                                 float* __restrict__ outp) {
    int t = threadIdx.x, blk = blockIdx.x;
    int b = blk >> 9, ms = (blk >> 6) & 7, nb = blk & 63;
    int n0 = nb * 64, mbase = ms * 512;
    int lane = t & 63, wid = t >> 6, g = lane >> 4, ln = lane & 15;

    const unsigned short* krp = kg + (size_t)(b * 4096 + n0 + wid * 16 + ln) * 64;
    short8 kb0 = *(const short8*)(krp + 8 * g);
    short8 kb1 = *(const short8*)(krp + 32 + 8 * g);

    const unsigned short* qbase = qg + (size_t)(b * 4096 + mbase + ln) * 64 + 8 * g;
    const unsigned short* vtb = vtg + (size_t)b * 262144 + mbase;   // [c][m], c-row = fb*16+ln
    const float* lrb = lrbuf + b * 4096 + mbase + 4 * g;

    // current-iteration regs (chunk 0)
    short8 as0 = *(const short8*)(qbase);
    short8 as1 = *(const short8*)(qbase + 32);
    short4b vb0 = *(const short4b*)(vtb + (size_t)(ln) * 4096 + 4 * g);
    short4b vb1 = *(const short4b*)(vtb + (size_t)(16 + ln) * 4096 + 4 * g);
    short4b vb2 = *(const short4b*)(vtb + (size_t)(32 + ln) * 4096 + 4 * g);
    short4b vb3 = *(const short4b*)(vtb + (size_t)(48 + ln) * 4096 + 4 * g);
    f32x4 lcur = *(const f32x4*)(lrb);

    f32x4 z = {0.f, 0.f, 0.f, 0.f};
    f32x4 oacc[4] = {z, z, z, z};

    for (int mc = 0; mc < 32; ++mc) {
        short8 nas0, nas1;
        short4b nvb0, nvb1, nvb2, nvb3;
        f32x4 lnext;
        if (mc < 31) {   // register prefetch of chunk mc+1
            int moff = (mc + 1) * 16;
            const unsigned short* qp = qbase + (size_t)moff * 64;
            nas0 = *(const short8*)(qp);
            nas1 = *(const short8*)(qp + 32);
            const unsigned short* vp = vtb + moff + 4 * g;
            nvb0 = *(const short4b*)(vp + (size_t)(ln) * 4096);
            nvb1 = *(const short4b*)(vp + (size_t)(16 + ln) * 4096);
            nvb2 = *(const short4b*)(vp + (size_t)(32 + ln) * 4096);
            nvb3 = *(const short4b*)(vp + (size_t)(48 + ln) * 4096);
            lnext = *(const f32x4*)(lrb + moff);
        }
        // QK^T, C-init = lr -> p = exp2(e)
        f32x4 e = MFMA32(as1, kb1, MFMA32(as0, kb0, lcur));
        float p0 = EXP2(e[0]), p1 = EXP2(e[1]), p2 = EXP2(e[2]), p3 = EXP2(e[3]);
        u32x2 pw = { pack2t(p0, p1), pack2t(p2, p3) };
        short4b pa = __builtin_bit_cast(short4b, pw);   // K=16 A-frag, in-register
        oacc[0] = MFMA16(pa, vb0, oacc[0]);
        oacc[1] = MFMA16(pa, vb1, oacc[1]);
        oacc[2] = MFMA16(pa, vb2, oacc[2]);
        oacc[3] = MFMA16(pa, vb3, oacc[3]);
        as0 = nas0; as1 = nas1;
        vb0 = nvb0; vb1 = nvb1; vb2 = nvb2; vb3 = nvb3;
        lcur = lnext;
    }

    float gm = gamma[0];
    int nr = b * 4096 + n0 + wid * 16 + 4 * g;
    #pragma unroll
    for (int fb = 0; fb < 4; ++fb) {
        #pragma unroll
        for (int r = 0; r < 4; ++r)
            unsafeAtomicAdd(outp + (size_t)(nr + r) * 64 + fb * 16 + ln, gm * oacc[fb][r]);
    }
}

extern "C" void kernel_launch(void* const* d_in, const int* in_sizes, int n_in,
                              void* d_out, int out_size, void* d_ws, size_t ws_size,
                              hipStream_t stream) {
    const float* x  = (const float*)d_in[0];
    const float* Wq = (const float*)d_in[1];
    const float* bq = (const float*)d_in[2];
    const float* Wk = (const float*)d_in[3];
    const float* bk = (const float*)d_in[4];
    const float* Wv = (const float*)d_in[5];
    const float* bv = (const float*)d_in[6];
    const float* gm = (const float*)d_in[7];
    char* ws = (char*)d_ws;
    float* outp = (float*)d_out;

    unsigned short* qg  = (unsigned short*)(ws + OFF_Q);
    unsigned short* kg  = (unsigned short*)(ws + OFF_K);
    unsigned short* vtg = (unsigned short*)(ws + OFF_VT);
    unsigned short* wt  = (unsigned short*)(ws + OFF_WT);
    float* sbuf         = (float*)(ws + OFF_S);
    float* lrbuf        = (float*)(ws + OFF_LR);

    k0z<<<64, 256, 0, stream>>>(Wq, Wk, Wv, wt, sbuf);
    k1_proj<<<768, 256, 0, stream>>>(x, wt, bq, bk, bv, qg, kg, vtg);
    k2_rowsum<<<2048, 256, 0, stream>>>(qg, kg, sbuf);
    r2_init<<<1024, 256, 0, stream>>>(sbuf, lrbuf, x, outp);
    k3_out<<<2048, 256, 0, stream>>>(qg, kg, vtg, lrbuf, gm, outp);
}

// Round 7
// 134.509 us; speedup vs baseline: 2.3882x; 2.3882x over previous
//
#include <hip/hip_runtime.h>
#include <hip/hip_bf16.h>

// PAM module: B=4, N=4096 (64x64), C=64.
// out[b,n,c] = gamma * sum_m softmax_row(q@k^T)[m,n] * v[m,c] + x[b,n,c]
//
// bf16 MFMA; energy recomputed. log2e folded into Wq/bq; softmax normalizer
// folded into QK MFMA C-init (lr = -log2(rowsum)); P built in registers
// (K=16 PV MFMA identity), truncation bf16 pack. Streamed operands go
// coalesced-global -> double-buffered swizzled LDS (1 barrier/iter);
// pinned per-wave fragments load once from global.
//  k0z: W -> W^T bf16 (Wq scaled by log2e), zero s-buffer
//  k1 : per-projection blocks (grid 768): q,k row-major bf16; v^T [c][n] bf16
//  k2 : partial rowsums, n-split 4; waves n-DISTRIBUTED (no LDS read dup)
//  r2 : lr = -log2(s) ; out <- x
//  k3 : out += gamma * exp2(e'+lr) @ v ; m-split 4, dbuf LDS, reg-P

typedef __attribute__((ext_vector_type(8))) short short8;
typedef __attribute__((ext_vector_type(4))) short short4b;
typedef __attribute__((ext_vector_type(4))) float f32x4;
typedef __attribute__((ext_vector_type(4))) unsigned int u32x4;
typedef __attribute__((ext_vector_type(2))) unsigned int u32x2;

#define DEV static __device__ __forceinline__
#define LOG2E 1.4426950408889634f

DEV unsigned short f2bf(float f) {
    __hip_bfloat16 h = __float2bfloat16(f);
    return __builtin_bit_cast(unsigned short, h);
}
DEV unsigned int pack2(float lo, float hi) {
    return (unsigned int)f2bf(lo) | ((unsigned int)f2bf(hi) << 16);
}
DEV unsigned int pack2t(float lo, float hi) {   // truncation-pack (P>=0, no NaN)
    unsigned int ul = __builtin_bit_cast(unsigned int, lo);
    unsigned int uh = __builtin_bit_cast(unsigned int, hi);
    return (uh & 0xffff0000u) | (ul >> 16);
}
DEV f32x4 MFMA32(short8 a, short8 b, f32x4 c) {
    return __builtin_amdgcn_mfma_f32_16x16x32_bf16(a, b, c, 0, 0, 0);
}
DEV f32x4 MFMA16(short4b a, short4b b, f32x4 c) {
#if __has_builtin(__builtin_amdgcn_mfma_f32_16x16x16_bf16)
    return __builtin_amdgcn_mfma_f32_16x16x16_bf16(a, b, c, 0, 0, 0);
#else
    return __builtin_amdgcn_mfma_f32_16x16x16bf16_1k(a, b, c, 0, 0, 0);
#endif
}
DEV float EXP2(float x) {
#if __has_builtin(__builtin_amdgcn_exp2f)
    return __builtin_amdgcn_exp2f(x);
#else
    return exp2f(x);
#endif
}

// ws layout (bytes)
#define OFF_Q    0u          // [16384][64] bf16 = 2 MB  (q' = log2e * (xWq+bq))
#define OFF_K    2097152u    // [16384][64] bf16 = 2 MB
#define OFF_VT   4194304u    // [4][64][4096] bf16 = 2 MB
#define OFF_WT   6291456u    // [3][64][64] bf16 = 24 KB
#define OFF_S    6316032u    // [16384] f32 = 64 KB (row sums, atomic)
#define OFF_LR   6381568u    // [16384] f32 = 64 KB (lr = -log2 s)

// ---------------- k0z: weight transpose (+log2e on Wq) + zero s ----------------
__global__ __launch_bounds__(256) void k0z(const float* __restrict__ Wq,
                                           const float* __restrict__ Wk,
                                           const float* __restrict__ Wv,
                                           unsigned short* __restrict__ wt,
                                           float* __restrict__ sbuf) {
    int e = blockIdx.x * 256 + threadIdx.x;   // grid 64 -> [0,16384)
    sbuf[e] = 0.0f;
    if (e < 3 * 4096) {
        int w3 = e >> 12, rem = e & 4095, f = rem >> 6, c = rem & 63;
        const float* W = (w3 == 0) ? Wq : (w3 == 1) ? Wk : Wv;
        float s = (w3 == 0) ? LOG2E : 1.0f;
        wt[e] = f2bf(W[c * 64 + f] * s);   // wt[w3][f][c] = W[c][f] * s
    }
}

// ---------------- k1: projections, one projection per block (grid 768) ----------------
__global__ __launch_bounds__(256) void k1_proj(const float* __restrict__ x,
                                               const unsigned short* __restrict__ wt,
                                               const float* __restrict__ bq,
                                               const float* __restrict__ bk,
                                               const float* __restrict__ bv,
                                               unsigned short* __restrict__ qg,
                                               unsigned short* __restrict__ kg,
                                               unsigned short* __restrict__ vtg) {
    __shared__ __align__(16) char XT[8192];
    __shared__ __align__(16) char WT1[8192];
    __shared__ __align__(16) char VTILE[9216];
    int t = threadIdx.x, blk = blockIdx.x;
    int w3 = blk >> 8, rb = blk & 255;

    {   // stage x tile (fp32 -> bf16, swizzled)
        int m = t >> 2, q4 = t & 3;
        const f32x4* xs = (const f32x4*)(x + (size_t)(rb * 64 + m) * 64 + q4 * 16);
        f32x4 fa = xs[0], f2 = xs[1], fc = xs[2], fd = xs[3];
        u32x4 u0 = { pack2(fa[0],fa[1]), pack2(fa[2],fa[3]), pack2(f2[0],f2[1]), pack2(f2[2],f2[3]) };
        u32x4 u1 = { pack2(fc[0],fc[1]), pack2(fc[2],fc[3]), pack2(fd[0],fd[1]), pack2(fd[2],fd[3]) };
        int sw = (m & 7) << 4;
        *(u32x4*)(XT + m * 128 + ((q4 * 32) ^ sw)) = u0;
        *(u32x4*)(XT + m * 128 + ((q4 * 32 + 16) ^ sw)) = u1;
    }
    {   // stage this block's W^T
        int f = t >> 2, q4 = t & 3;
        const u32x4* s = (const u32x4*)(wt + w3 * 4096 + f * 64 + q4 * 16);
        u32x4 u0 = s[0], u1 = s[1];
        int sw = (f & 7) << 4;
        *(u32x4*)(WT1 + f * 128 + ((q4 * 32) ^ sw)) = u0;
        *(u32x4*)(WT1 + f * 128 + ((q4 * 32 + 16) ^ sw)) = u1;
    }
    __syncthreads();

    int lane = t & 63, wid = t >> 6, g = lane >> 4, ln = lane & 15;
    int arow = wid * 16 + ln;
    short8 a0 = *(const short8*)(XT + arow * 128 + ((16 * g) ^ ((arow & 7) << 4)));
    short8 a1 = *(const short8*)(XT + arow * 128 + ((64 + 16 * g) ^ ((arow & 7) << 4)));
    const float* bias = (w3 == 0) ? bq : (w3 == 1) ? bk : bv;
    float bscale = (w3 == 0) ? LOG2E : 1.0f;

    #pragma unroll
    for (int fb = 0; fb < 4; ++fb) {
        int frow = fb * 16 + ln;
        short8 b0 = *(const short8*)(WT1 + frow * 128 + ((16 * g) ^ ((frow & 7) << 4)));
        short8 b1 = *(const short8*)(WT1 + frow * 128 + ((64 + 16 * g) ^ ((frow & 7) << 4)));
        f32x4 acc = {0.f, 0.f, 0.f, 0.f};
        acc = MFMA32(a0, b0, acc);
        acc = MFMA32(a1, b1, acc);
        float bval = bias[frow] * bscale;
        if (w3 < 2) {
            unsigned short* dst = (w3 == 0) ? qg : kg;
            int gr = rb * 64 + wid * 16 + 4 * g;
            #pragma unroll
            for (int r = 0; r < 4; ++r)
                dst[(size_t)(gr + r) * 64 + frow] = f2bf(acc[r] + bval);
        } else {
            unsigned short* vt = (unsigned short*)VTILE;
            int mloc = wid * 16 + 4 * g;
            #pragma unroll
            for (int r = 0; r < 4; ++r)
                vt[frow * 72 + mloc + r] = f2bf(acc[r] + bval);
        }
    }
    if (w3 == 2) {   // block-uniform branch
        __syncthreads();
        int f = t >> 2, mq = t & 3;
        u32x4 u0 = *(const u32x4*)(VTILE + f * 144 + mq * 32);
        u32x4 u1 = *(const u32x4*)(VTILE + f * 144 + mq * 32 + 16);
        int b = rb >> 6, n0 = (rb & 63) * 64;
        unsigned short* dst = vtg + (size_t)b * 262144 + f * 4096 + n0 + mq * 16;
        *(u32x4*)(dst) = u0;
        *(u32x4*)(dst + 8) = u1;
    }
}

// ---------------- k2: partial row sums, n-distributed waves ----------------
// grid 1024: blk = b*256 + ns*64 + mb. Block owns 64 m; wave pins A-frags for
// ALL 64 m (32 VGPR) and computes only its own 2 n-subtiles per 128-n chunk
// (no cross-wave LDS read duplication). 8 iters, dbuf, 1 barrier/iter.
__global__ __launch_bounds__(256, 4) void k2_rowsum(const unsigned short* __restrict__ qg,
                                                    const unsigned short* __restrict__ kg,
                                                    float* __restrict__ sbuf) {
    __shared__ __align__(16) char KD[2][16384];   // [128 n][128B c] swz
    int t = threadIdx.x, blk = blockIdx.x;
    int b = blk >> 8, ns = (blk >> 6) & 3, mb = blk & 63;
    int m0 = mb * 64, nbase = ns * 1024;
    int lane = t & 63, wid = t >> 6, g = lane >> 4, ln = lane & 15;

    // pinned A-frags: a[mi][h] = q[m0 + mi*16 + ln][c = h*32 + 8g ..]
    short8 a[4][2];
    {
        const unsigned short* qr = qg + (size_t)(b * 4096 + m0 + ln) * 64;
        #pragma unroll
        for (int mi = 0; mi < 4; ++mi) {
            a[mi][0] = *(const short8*)(qr + mi * 1024 + 8 * g);
            a[mi][1] = *(const short8*)(qr + mi * 1024 + 32 + 8 * g);
        }
    }
    // staging indices: thread covers 64 B of one LDS row
    int kr = t >> 1, kh = t & 1, ksw = (kr & 7) << 4;
    const unsigned short* kbase = kg + (size_t)(b * 4096 + nbase) * 64;
    {   // chunk 0
        const u32x4* s = (const u32x4*)(kbase + (size_t)kr * 64 + kh * 32);
        u32x4 u0 = s[0], u1 = s[1], u2 = s[2], u3 = s[3];
        char* d = KD[0] + kr * 128;
        *(u32x4*)(d + ((kh * 64 +  0) ^ ksw)) = u0;
        *(u32x4*)(d + ((kh * 64 + 16) ^ ksw)) = u1;
        *(u32x4*)(d + ((kh * 64 + 32) ^ ksw)) = u2;
        *(u32x4*)(d + ((kh * 64 + 48) ^ ksw)) = u3;
    }
    __syncthreads();

    f32x4 z = {0.f, 0.f, 0.f, 0.f};
    f32x4 acc[4] = {z, z, z, z};
    int buf = 0;
    for (int nc = 0; nc < 8; ++nc) {
        int nn = (nc < 7) ? nc + 1 : nc;
        const u32x4* s = (const u32x4*)(kbase + (size_t)(nn * 128 + kr) * 64 + kh * 32);
        u32x4 p0 = s[0], p1 = s[1], p2 = s[2], p3 = s[3];
        const char* kt = KD[buf];
        #pragma unroll
        for (int j = 0; j < 2; ++j) {
            int brow = (2 * wid + j) * 16 + ln, bsw = (brow & 7) << 4;
            short8 kb0 = *(const short8*)(kt + brow * 128 + ((16 * g) ^ bsw));
            short8 kb1 = *(const short8*)(kt + brow * 128 + ((64 + 16 * g) ^ bsw));
            #pragma unroll
            for (int mi = 0; mi < 4; ++mi) {
                f32x4 e = MFMA32(a[mi][1], kb1, MFMA32(a[mi][0], kb0, z));
                acc[mi][0] += EXP2(e[0]); acc[mi][1] += EXP2(e[1]);
                acc[mi][2] += EXP2(e[2]); acc[mi][3] += EXP2(e[3]);
            }
        }
        char* d = KD[buf ^ 1] + kr * 128;
        *(u32x4*)(d + ((kh * 64 +  0) ^ ksw)) = p0;
        *(u32x4*)(d + ((kh * 64 + 16) ^ ksw)) = p1;
        *(u32x4*)(d + ((kh * 64 + 32) ^ ksw)) = p2;
        *(u32x4*)(d + ((kh * 64 + 48) ^ ksw)) = p3;
        __syncthreads();
        buf ^= 1;
    }
    // reduce over ln (n-columns) within each group, then atomic per m
    #pragma unroll
    for (int mi = 0; mi < 4; ++mi) {
        #pragma unroll
        for (int msk = 1; msk < 16; msk <<= 1) {
            acc[mi][0] += __shfl_xor(acc[mi][0], msk);
            acc[mi][1] += __shfl_xor(acc[mi][1], msk);
            acc[mi][2] += __shfl_xor(acc[mi][2], msk);
            acc[mi][3] += __shfl_xor(acc[mi][3], msk);
        }
    }
    if (ln == 0) {
        #pragma unroll
        for (int mi = 0; mi < 4; ++mi) {
            float* base = sbuf + b * 4096 + m0 + mi * 16 + 4 * g;
            unsafeAtomicAdd(base + 0, acc[mi][0]);
            unsafeAtomicAdd(base + 1, acc[mi][1]);
            unsafeAtomicAdd(base + 2, acc[mi][2]);
            unsafeAtomicAdd(base + 3, acc[mi][3]);
        }
    }
}

// ---------------- r2: lr = -log2(s) ; out <- x ----------------
__global__ __launch_bounds__(256) void r2_init(const float* __restrict__ sbuf,
                                               float* __restrict__ lrbuf,
                                               const float* __restrict__ x,
                                               float* __restrict__ outp) {
    int tid = blockIdx.x * 256 + threadIdx.x;   // grid 1024
    if (tid < 16384) lrbuf[tid] = -__log2f(sbuf[tid]);
    f32x4 v = *(const f32x4*)(x + 4 * (size_t)tid);
    *(f32x4*)(outp + 4 * (size_t)tid) = v;
}

// ---------------- k3: out += gamma * exp2(e'+lr) @ v  (m-split 4, dbuf, reg-P) ----------------
// grid 1024: blk = b*256 + ms*64 + nb. Wave owns 16 n (k frags pinned from
// global, one-time). Streams 16 chunks of 64 m: q + v^T through dbuf LDS.
__global__ __launch_bounds__(256, 4) void k3_out(const unsigned short* __restrict__ qg,
                                                 const unsigned short* __restrict__ kg,
                                                 const unsigned short* __restrict__ vtg,
                                                 const float* __restrict__ lrbuf,
                                                 const float* __restrict__ gamma,
                                                 float* __restrict__ outp) {
    __shared__ __align__(16) char QD[2][8192];   // [64 m][128B c] swz
    __shared__ __align__(16) char VD[2][8192];   // [64 c][128B m] swz
    int t = threadIdx.x, blk = blockIdx.x;
    int b = blk >> 8, ms = (blk >> 6) & 3, nb = blk & 63;
    int n0 = nb * 64, mbase = ms * 1024;
    int lane = t & 63, wid = t >> 6, g = lane >> 4, ln = lane & 15;

    // pinned k B-frags (one-time global load)
    const unsigned short* krp = kg + (size_t)(b * 4096 + n0 + wid * 16 + ln) * 64;
    short8 kb0 = *(const short8*)(krp + 8 * g);
    short8 kb1 = *(const short8*)(krp + 32 + 8 * g);

    // staging indices (row = t>>2 serves q m-row and vT c-row), 32 B/thread each
    int row = t >> 2, q4 = t & 3, sw = (row & 7) << 4;
    const unsigned short* qbase = qg + (size_t)(b * 4096 + mbase + row) * 64 + q4 * 16;
    const unsigned short* vbase = vtg + (size_t)b * 262144 + (size_t)row * 4096 + mbase + q4 * 16;
    {   // chunk 0
        u32x4 q0 = *(const u32x4*)(qbase);
        u32x4 q1 = *(const u32x4*)(qbase + 8);
        u32x4 v0 = *(const u32x4*)(vbase);
        u32x4 v1 = *(const u32x4*)(vbase + 8);
        *(u32x4*)(QD[0] + row * 128 + ((q4 * 32) ^ sw)) = q0;
        *(u32x4*)(QD[0] + row * 128 + ((q4 * 32 + 16) ^ sw)) = q1;
        *(u32x4*)(VD[0] + row * 128 + ((q4 * 32) ^ sw)) = v0;
        *(u32x4*)(VD[0] + row * 128 + ((q4 * 32 + 16) ^ sw)) = v1;
    }
    const float* lrb = lrbuf + b * 4096 + mbase + 4 * g;
    f32x4 lc0 = *(const f32x4*)(lrb);
    f32x4 lc1 = *(const f32x4*)(lrb + 16);
    f32x4 lc2 = *(const f32x4*)(lrb + 32);
    f32x4 lc3 = *(const f32x4*)(lrb + 48);
    __syncthreads();

    f32x4 z = {0.f, 0.f, 0.f, 0.f};
    f32x4 oacc[4] = {z, z, z, z};
    int buf = 0;
    for (int mc = 0; mc < 16; ++mc) {
        int nx = (mc < 15) ? mc + 1 : mc;
        // register prefetch of next chunk (q, vT, lr)
        u32x4 qp0 = *(const u32x4*)(qbase + (size_t)nx * 64 * 64);
        u32x4 qp1 = *(const u32x4*)(qbase + (size_t)nx * 64 * 64 + 8);
        u32x4 vp0 = *(const u32x4*)(vbase + nx * 64);
        u32x4 vp1 = *(const u32x4*)(vbase + nx * 64 + 8);
        f32x4 ln0 = *(const f32x4*)(lrb + nx * 64);
        f32x4 ln1 = *(const f32x4*)(lrb + nx * 64 + 16);
        f32x4 ln2 = *(const f32x4*)(lrb + nx * 64 + 32);
        f32x4 ln3 = *(const f32x4*)(lrb + nx * 64 + 48);

        const char* qt = QD[buf];
        const char* vt = VD[buf];
        #pragma unroll
        for (int s = 0; s < 4; ++s) {
            int qrow = s * 16 + ln, qsw = (qrow & 7) << 4;
            short8 as0 = *(const short8*)(qt + qrow * 128 + ((16 * g) ^ qsw));
            short8 as1 = *(const short8*)(qt + qrow * 128 + ((64 + 16 * g) ^ qsw));
            f32x4 lv = (s == 0) ? lc0 : (s == 1) ? lc1 : (s == 2) ? lc2 : lc3;
            f32x4 e = MFMA32(as1, kb1, MFMA32(as0, kb0, lv));
            float p0 = EXP2(e[0]), p1 = EXP2(e[1]), p2 = EXP2(e[2]), p3 = EXP2(e[3]);
            u32x2 pw = { pack2t(p0, p1), pack2t(p2, p3) };
            short4b pa = __builtin_bit_cast(short4b, pw);
            #pragma unroll
            for (int fb = 0; fb < 4; ++fb) {
                int vrow = fb * 16 + ln;
                short4b vb = *(const short4b*)(vt + vrow * 128 + ((s * 32 + g * 8) ^ ((vrow & 7) << 4)));
                oacc[fb] = MFMA16(pa, vb, oacc[fb]);
            }
        }
        // write prefetched chunk into other buffer
        *(u32x4*)(QD[buf ^ 1] + row * 128 + ((q4 * 32) ^ sw)) = qp0;
        *(u32x4*)(QD[buf ^ 1] + row * 128 + ((q4 * 32 + 16) ^ sw)) = qp1;
        *(u32x4*)(VD[buf ^ 1] + row * 128 + ((q4 * 32) ^ sw)) = vp0;
        *(u32x4*)(VD[buf ^ 1] + row * 128 + ((q4 * 32 + 16) ^ sw)) = vp1;
        lc0 = ln0; lc1 = ln1; lc2 = ln2; lc3 = ln3;
        __syncthreads();
        buf ^= 1;
    }

    float gm = gamma[0];
    int nr = b * 4096 + n0 + wid * 16 + 4 * g;
    #pragma unroll
    for (int fb = 0; fb < 4; ++fb) {
        #pragma unroll
        for (int r = 0; r < 4; ++r)
            unsafeAtomicAdd(outp + (size_t)(nr + r) * 64 + fb * 16 + ln, gm * oacc[fb][r]);
    }
}

extern "C" void kernel_launch(void* const* d_in, const int* in_sizes, int n_in,
                              void* d_out, int out_size, void* d_ws, size_t ws_size,
                              hipStream_t stream) {
    const float* x  = (const float*)d_in[0];
    const float* Wq = (const float*)d_in[1];
    const float* bq = (const float*)d_in[2];
    const float* Wk = (const float*)d_in[3];
    const float* bk = (const float*)d_in[4];
    const float* Wv = (const float*)d_in[5];
    const float* bv = (const float*)d_in[6];
    const float* gm = (const float*)d_in[7];
    char* ws = (char*)d_ws;
    float* outp = (float*)d_out;

    unsigned short* qg  = (unsigned short*)(ws + OFF_Q);
    unsigned short* kg  = (unsigned short*)(ws + OFF_K);
    unsigned short* vtg = (unsigned short*)(ws + OFF_VT);
    unsigned short* wt  = (unsigned short*)(ws + OFF_WT);
    float* sbuf         = (float*)(ws + OFF_S);
    float* lrbuf        = (float*)(ws + OFF_LR);

    k0z<<<64, 256, 0, stream>>>(Wq, Wk, Wv, wt, sbuf);
    k1_proj<<<768, 256, 0, stream>>>(x, wt, bq, bk, bv, qg, kg, vtg);
    k2_rowsum<<<1024, 256, 0, stream>>>(qg, kg, sbuf);
    r2_init<<<1024, 256, 0, stream>>>(sbuf, lrbuf, x, outp);
    k3_out<<<1024, 256, 0, stream>>>(qg, kg, vtg, lrbuf, gm, outp);
}